// Round 3
// baseline (209.493 us; speedup 1.0000x reference)
//
#include <hip/hip_runtime.h>
#include <hip/hip_bf16.h>
#include <stdint.h>

#define H 128
#define NE 500000

typedef __bf16 bf16x8 __attribute__((ext_vector_type(8)));
typedef float f32x4 __attribute__((ext_vector_type(4)));

__device__ __forceinline__ float fast_silu(float x) {
    float e = __builtin_amdgcn_exp2f(x * -1.44269504088896341f);
    return x * __builtin_amdgcn_rcpf(1.0f + e);
}

__device__ __forceinline__ unsigned f2bf(float f) {
    unsigned u = __builtin_bit_cast(unsigned, f);
    return (u + 0x7FFFu + ((u >> 16) & 1u)) >> 16;
}

// ---------------------------------------------------------------------------
// Prep: P1[r][c] = emb[r] @ w_lin[0:128][c] + b_lin[c]
//       P2[r][c] = emb[r] @ w_lin[128:256][c]
//       w3t[c][k] = bf16(w_lin[256+k][c])   (transposed, bf16-pair packed)
// ---------------------------------------------------------------------------
__global__ void prep_kernel(const float* __restrict__ emb,
                            const float* __restrict__ w_lin,
                            const float* __restrict__ b_lin,
                            float* __restrict__ P1, float* __restrict__ P2,
                            unsigned* __restrict__ w3t) {
    int b = blockIdx.x, t = threadIdx.x;
    if (b < 95) {
        int c = t & (H - 1);
        int half = t >> 7;
        const float* wb = w_lin + half * (H * H);
        float a = half ? 0.0f : b_lin[c];
        #pragma unroll 4
        for (int k = 0; k < H; ++k)
            a = fmaf(emb[b * H + k], wb[k * H + c], a);
        (half ? P2 : P1)[b * H + c] = a;
    } else {
        int idx = (b - 95) * 256 + t;      // row c = idx>>6, k-pair = idx&63
        int c = idx >> 6;
        int k = (idx & 63) * 2;
        unsigned lo = f2bf(w_lin[(2 * H + k) * H + c]);
        unsigned hi = f2bf(w_lin[(2 * H + k + 1) * H + c]);
        w3t[idx] = lo | (hi << 16);
    }
}

// ---------------------------------------------------------------------------
// Main: 128 edges x 128 outputs per block, 4 waves (2 edge x 2 col).
// h-fragments computed per-lane IN REGISTERS (no LDS h, one barrier total).
//   acc[ef][cf] = mfma(W3frag[cf], hfrag[ef])  -> out^T fragment layout.
// ---------------------------------------------------------------------------
__global__ __launch_bounds__(256, 3)
void edge_kernel(const float* __restrict__ rbf,
                 const int* __restrict__ ei, const int* __restrict__ ej,
                 const int* __restrict__ xin,
                 const float* __restrict__ w_rbf, const float* __restrict__ b_rbf,
                 const float* __restrict__ P1, const float* __restrict__ P2,
                 const unsigned* __restrict__ w3t,
                 float* __restrict__ out) {
    __shared__ float rbf_s[128 * 7];     // stride-7: conflict-free 6-scalar reads
    __shared__ float wr_s[6 * H];        // w_rbf [k][c]
    __shared__ float br_s[H];
    __shared__ int xi_s[128];
    __shared__ int xj_s[128];

    const int tid = threadIdx.x;
    const int e0 = blockIdx.x * 128;

    // ---- stage rbf (coalesced 3 dwords/thread) ----
    const int gbase = e0 * 6;
    #pragma unroll
    for (int k = 0; k < 3; ++k) {
        int d = tid + k * 256;                 // 0..767
        float v = 0.0f;
        if (gbase + d < NE * 6) v = rbf[gbase + d];
        rbf_s[(d / 6) * 7 + (d % 6)] = v;
    }
    // ---- stage w_rbf, b_rbf ----
    #pragma unroll
    for (int k = 0; k < 3; ++k) {
        int d = tid + k * 256;
        wr_s[d] = w_rbf[d];
    }
    if (tid < H) br_s[tid] = b_rbf[tid];
    // ---- per-edge embedding row indices (split gather across waves) ----
    if (tid < 128) {
        int e = e0 + tid;
        xi_s[tid] = (e < NE) ? xin[ei[e]] : 0;
    } else {
        int t = tid - 128;
        int e = e0 + t;
        xj_s[t] = (e < NE) ? xin[ej[e]] : 0;
    }
    __syncthreads();

    const int wave = tid >> 6;
    const int lane = tid & 63;
    const int we = wave >> 1;
    const int wc = wave & 1;
    const int l15 = lane & 15;
    const int lq = lane >> 4;

    // ---- per-lane rbf rows for my 4 edge-fragments (held in regs) ----
    float rk[4][6];
    #pragma unroll
    for (int ef = 0; ef < 4; ++ef) {
        int el = we * 64 + ef * 16 + l15;
        #pragma unroll
        for (int k = 0; k < 6; ++k)
            rk[ef][k] = rbf_s[el * 7 + k];
    }

    f32x4 acc[4][4];
    #pragma unroll
    for (int a = 0; a < 4; ++a)
        #pragma unroll
        for (int b = 0; b < 4; ++b)
            acc[a][b] = (f32x4){0.f, 0.f, 0.f, 0.f};

    // ---- K loop: ks selects 32 k-columns; lane owns 8 of them (lq*8) ----
    #pragma unroll
    for (int ks = 0; ks < 4; ++ks) {
        const int c0 = ks * 32 + lq * 8;       // my 8 h-columns this ks

        // W3 fragments for this ks (L1-resident table, no LDS)
        bf16x8 bfr[4];
        #pragma unroll
        for (int cf = 0; cf < 4; ++cf) {
            int c = wc * 64 + cf * 16 + l15;
            bfr[cf] = *(const bf16x8*)((const char*)w3t + c * 256 + ks * 64 + lq * 16);
        }

        // w_rbf coefficients for my 8 columns (broadcast LDS reads)
        f32x4 w0[6], w1[6];
        #pragma unroll
        for (int k = 0; k < 6; ++k) {
            w0[k] = *(const f32x4*)(wr_s + k * H + c0);
            w1[k] = *(const f32x4*)(wr_s + k * H + c0 + 4);
        }
        f32x4 b0 = *(const f32x4*)(br_s + c0);
        f32x4 b1 = *(const f32x4*)(br_s + c0 + 4);

        #pragma unroll
        for (int ef = 0; ef < 4; ++ef) {
            f32x4 s0 = b0, s1 = b1;
            #pragma unroll
            for (int k = 0; k < 6; ++k) {
                s0 += rk[ef][k] * w0[k];
                s1 += rk[ef][k] * w1[k];
            }
            bf16x8 a;
            a[0] = (__bf16)fast_silu(s0[0]);
            a[1] = (__bf16)fast_silu(s0[1]);
            a[2] = (__bf16)fast_silu(s0[2]);
            a[3] = (__bf16)fast_silu(s0[3]);
            a[4] = (__bf16)fast_silu(s1[0]);
            a[5] = (__bf16)fast_silu(s1[1]);
            a[6] = (__bf16)fast_silu(s1[2]);
            a[7] = (__bf16)fast_silu(s1[3]);
            #pragma unroll
            for (int cf = 0; cf < 4; ++cf)
                acc[ef][cf] = __builtin_amdgcn_mfma_f32_16x16x32_bf16(
                    bfr[cf], a, acc[ef][cf], 0, 0, 0);
        }
    }

    // ---- epilogue: lane holds 4 consecutive cols for one edge -> float4 ----
    #pragma unroll
    for (int ef = 0; ef < 4; ++ef) {
        const int el = we * 64 + ef * 16 + l15;
        const int e = e0 + el;
        if (e < NE) {
            const float* p1 = P1 + xi_s[el] * H;
            const float* p2 = P2 + xj_s[el] * H;
            float* op = out + (size_t)e * H;
            #pragma unroll
            for (int cf = 0; cf < 4; ++cf) {
                const int cb = wc * 64 + cf * 16 + lq * 4;
                f32x4 q1 = *(const f32x4*)(p1 + cb);
                f32x4 q2 = *(const f32x4*)(p2 + cb);
                f32x4 o;
                #pragma unroll
                for (int r = 0; r < 4; ++r)
                    o[r] = fast_silu(acc[ef][cf][r] + q1[r] + q2[r]);
                *(f32x4*)(op + cb) = o;
            }
        }
    }
}

extern "C" void kernel_launch(void* const* d_in, const int* in_sizes, int n_in,
                              void* d_out, int out_size, void* d_ws, size_t ws_size,
                              hipStream_t stream) {
    const int*   x      = (const int*)d_in[0];
    const float* rbf    = (const float*)d_in[1];
    const int*   ei     = (const int*)d_in[2];
    const int*   ej     = (const int*)d_in[3];
    const float* emb    = (const float*)d_in[4];
    const float* w_rbf  = (const float*)d_in[5];
    const float* b_rbf  = (const float*)d_in[6];
    const float* w_lin  = (const float*)d_in[7];
    const float* b_lin  = (const float*)d_in[8];
    float* out = (float*)d_out;

    float*    P1  = (float*)d_ws;                 // 95*128 f32
    float*    P2  = P1 + 95 * H;                  // 95*128 f32
    unsigned* w3t = (unsigned*)(P2 + 95 * H);     // 128*64 u32 (bf16 pairs)

    prep_kernel<<<95 + 32, 256, 0, stream>>>(emb, w_lin, b_lin, P1, P2, w3t);

    int nblk = (NE + 127) / 128;                  // 3907
    edge_kernel<<<nblk, 256, 0, stream>>>(rbf, ei, ej, x, w_rbf, b_rbf,
                                          P1, P2, w3t, out);
}

// Round 4
// 158.397 us; speedup vs baseline: 1.3226x; 1.3226x over previous
//
#include <hip/hip_runtime.h>
#include <hip/hip_bf16.h>
#include <stdint.h>

#define H 128
#define NE 500000

typedef __bf16 bf16x8 __attribute__((ext_vector_type(8)));
typedef float f32x4 __attribute__((ext_vector_type(4)));

__device__ __forceinline__ float fast_silu(float x) {
    float e = __builtin_amdgcn_exp2f(x * -1.44269504088896341f);
    return x * __builtin_amdgcn_rcpf(1.0f + e);
}

__device__ __forceinline__ unsigned f2bf(float f) {
    unsigned u = __builtin_bit_cast(unsigned, f);
    return (u + 0x7FFFu + ((u >> 16) & 1u)) >> 16;
}

// ---------------------------------------------------------------------------
// Prep: blocks 0..94:  P1[b][c] = emb[b] @ w_lin[0:128][c] + b_lin[c]
//                      P2[b][c] = emb[b] @ w_lin[128:256][c]
//       blocks 95..126: w3t[c][k] = bf16(w_lin[256+k][c]) packed pairs
// ---------------------------------------------------------------------------
__global__ __launch_bounds__(256)
void prep_kernel(const float* __restrict__ emb,
                 const float* __restrict__ w_lin,
                 const float* __restrict__ b_lin,
                 float* __restrict__ P1, float* __restrict__ P2,
                 unsigned* __restrict__ w3t) {
    int b = blockIdx.x, t = threadIdx.x;
    if (b < 95) {
        __shared__ float emb_s[H];
        if (t < H) emb_s[t] = emb[b * H + t];
        __syncthreads();
        int c = t & (H - 1);
        int half = t >> 7;                   // 0 -> P1, 1 -> P2
        const float* wb = w_lin + half * (H * H) + c;
        float a = half ? 0.0f : b_lin[c];
        #pragma unroll 8
        for (int k = 0; k < H; ++k)
            a = fmaf(emb_s[k], wb[k * H], a);
        (half ? P2 : P1)[b * H + c] = a;
    } else {
        int idx = (b - 95) * 256 + t;        // row c = idx>>6, k-pair = idx&63
        int c = idx >> 6;
        int k = (idx & 63) * 2;
        unsigned lo = f2bf(w_lin[(2 * H + k) * H + c]);
        unsigned hi = f2bf(w_lin[(2 * H + k + 1) * H + c]);
        w3t[idx] = lo | (hi << 16);
    }
}

// ---------------------------------------------------------------------------
// Main: 128 edges x 128 outputs per block, 512 threads = 8 waves (4e x 2c).
// Round-2 proven structure (h via LDS, w3t clustered burst into regs),
// doubled wave count for occupancy: LDS 38KB -> 4 blocks/CU -> 32 waves/CU.
//   acc[ef][cf] = mfma(W3frag, hfrag) -> out^T layout -> float4 epilogue.
// ---------------------------------------------------------------------------
__global__ __launch_bounds__(512, 4)
void edge_kernel(const float* __restrict__ rbf,
                 const int* __restrict__ ei, const int* __restrict__ ej,
                 const int* __restrict__ xin,
                 const float* __restrict__ w_rbf, const float* __restrict__ b_rbf,
                 const float* __restrict__ P1, const float* __restrict__ P2,
                 const unsigned* __restrict__ w3t,
                 float* __restrict__ out) {
    __shared__ char hs[H * 256];        // bf16 h[128][128], XOR-swizzled, 32KB
    __shared__ float rbf_s[128 * 8];    // rbf padded to 8 f32/edge, 4KB
    __shared__ int xi_s[128];
    __shared__ int xj_s[128];

    const int tid = threadIdx.x;
    const int e0 = blockIdx.x * 128;

    // ---- stage rbf -> LDS, coalesced (768 dwords) ----
    const int gbase = e0 * 6;
    {
        int d = tid;
        float v = 0.0f;
        if (gbase + d < NE * 6) v = rbf[gbase + d];
        if (d < 768) rbf_s[(d / 6) * 8 + (d % 6)] = v;
        d = tid + 512;
        if (d < 768) {
            float v2 = 0.0f;
            if (gbase + d < NE * 6) v2 = rbf[gbase + d];
            rbf_s[(d / 6) * 8 + (d % 6)] = v2;
        }
    }

    // ---- per-edge node-embedding indices ----
    if (tid < 128) {
        int e = e0 + tid;
        xi_s[tid] = (e < NE) ? xin[ei[e]] : 0;
    } else if (tid < 256) {
        int t = tid - 128;
        int e = e0 + t;
        xj_s[t] = (e < NE) ? xin[ej[e]] : 0;
    }
    __syncthreads();

    // ---- h-phase: thread owns 8 cols x 4 edges ----
    {
        const int c8 = (tid & 15) * 8;
        const int eg = tid >> 4;           // 0..31 -> edges eg*4..+4
        f32x4 w0[6], w1[6];
        #pragma unroll
        for (int k = 0; k < 6; ++k) {
            w0[k] = *(const f32x4*)(w_rbf + k * H + c8);
            w1[k] = *(const f32x4*)(w_rbf + k * H + c8 + 4);
        }
        f32x4 b0 = *(const f32x4*)(b_rbf + c8);
        f32x4 b1 = *(const f32x4*)(b_rbf + c8 + 4);

        #pragma unroll
        for (int i = 0; i < 4; ++i) {
            int el = eg * 4 + i;
            f32x4 r03 = *(const f32x4*)(rbf_s + el * 8);
            float2 r45 = *(const float2*)(rbf_s + el * 8 + 4);
            float rk[6] = {r03[0], r03[1], r03[2], r03[3], r45.x, r45.y};
            f32x4 s0 = b0, s1 = b1;
            #pragma unroll
            for (int k = 0; k < 6; ++k) {
                s0 += rk[k] * w0[k];
                s1 += rk[k] * w1[k];
            }
            unsigned p0 = f2bf(fast_silu(s0[0])) | (f2bf(fast_silu(s0[1])) << 16);
            unsigned p1 = f2bf(fast_silu(s0[2])) | (f2bf(fast_silu(s0[3])) << 16);
            unsigned p2 = f2bf(fast_silu(s1[0])) | (f2bf(fast_silu(s1[1])) << 16);
            unsigned p3 = f2bf(fast_silu(s1[2])) | (f2bf(fast_silu(s1[3])) << 16);
            uint4 pv = {p0, p1, p2, p3};
            *(uint4*)(hs + el * 256 + ((c8 * 2) ^ ((el & 15) << 4))) = pv;
        }
    }

    // ---- W3^T fragments: ONE clustered burst into regs (keeps L2-hot) ----
    const int wave = tid >> 6;
    const int lane = tid & 63;
    const int we = wave & 3;          // edge group: 32 edges
    const int wc = wave >> 2;         // col group: 64 cols
    const int l15 = lane & 15;
    const int lq = lane >> 4;

    bf16x8 bfr[4][4];   // [cf][ks]
    #pragma unroll
    for (int cf = 0; cf < 4; ++cf) {
        int c = wc * 64 + cf * 16 + l15;
        #pragma unroll
        for (int ks = 0; ks < 4; ++ks)
            bfr[cf][ks] = *(const bf16x8*)((const char*)w3t + c * 256 + ks * 64 + lq * 16);
    }
    __syncthreads();

    // ---- MFMA: acc[ef][cf] = sum_ks W3frag x hfrag -> out^T tile ----
    f32x4 acc[2][4];
    #pragma unroll
    for (int a = 0; a < 2; ++a)
        #pragma unroll
        for (int b = 0; b < 4; ++b)
            acc[a][b] = (f32x4){0.f, 0.f, 0.f, 0.f};

    #pragma unroll
    for (int ks = 0; ks < 4; ++ks) {
        const int kb = ks * 64 + lq * 16;
        bf16x8 afr[2];
        #pragma unroll
        for (int ef = 0; ef < 2; ++ef) {
            int row = we * 32 + ef * 16 + l15;
            afr[ef] = *(const bf16x8*)(hs + row * 256 + (kb ^ ((row & 15) << 4)));
        }
        #pragma unroll
        for (int ef = 0; ef < 2; ++ef)
            #pragma unroll
            for (int cf = 0; cf < 4; ++cf)
                acc[ef][cf] = __builtin_amdgcn_mfma_f32_16x16x32_bf16(
                    bfr[cf][ks], afr[ef], acc[ef][cf], 0, 0, 0);
    }

    // ---- epilogue: lane holds 4 consecutive cols for one edge -> float4 ----
    #pragma unroll
    for (int ef = 0; ef < 2; ++ef) {
        const int el = we * 32 + ef * 16 + l15;
        const int e = e0 + el;
        if (e < NE) {
            const float* p1 = P1 + xi_s[el] * H;
            const float* p2 = P2 + xj_s[el] * H;
            float* op = out + (size_t)e * H;
            #pragma unroll
            for (int cf = 0; cf < 4; ++cf) {
                const int cb = wc * 64 + cf * 16 + lq * 4;
                f32x4 q1 = *(const f32x4*)(p1 + cb);
                f32x4 q2 = *(const f32x4*)(p2 + cb);
                f32x4 o;
                #pragma unroll
                for (int r = 0; r < 4; ++r)
                    o[r] = fast_silu(acc[ef][cf][r] + q1[r] + q2[r]);
                *(f32x4*)(op + cb) = o;
            }
        }
    }
}

extern "C" void kernel_launch(void* const* d_in, const int* in_sizes, int n_in,
                              void* d_out, int out_size, void* d_ws, size_t ws_size,
                              hipStream_t stream) {
    const int*   x      = (const int*)d_in[0];
    const float* rbf    = (const float*)d_in[1];
    const int*   ei     = (const int*)d_in[2];
    const int*   ej     = (const int*)d_in[3];
    const float* emb    = (const float*)d_in[4];
    const float* w_rbf  = (const float*)d_in[5];
    const float* b_rbf  = (const float*)d_in[6];
    const float* w_lin  = (const float*)d_in[7];
    const float* b_lin  = (const float*)d_in[8];
    float* out = (float*)d_out;

    float*    P1  = (float*)d_ws;                 // 95*128 f32
    float*    P2  = P1 + 95 * H;                  // 95*128 f32
    unsigned* w3t = (unsigned*)(P2 + 95 * H);     // 128*64 u32 (bf16 pairs)

    prep_kernel<<<95 + 32, 256, 0, stream>>>(emb, w_lin, b_lin, P1, P2, w3t);

    int nblk = (NE + 127) / 128;                  // 3907
    edge_kernel<<<nblk, 512, 0, stream>>>(rbf, ei, ej, x, w_rbf, b_rbf,
                                          P1, P2, w3t, out);
}